// Round 1
// baseline (1548.839 us; speedup 1.0000x reference)
//
#include <hip/hip_runtime.h>
#include <math.h>

#define N 8192
#define D 1024
#define INV_T 14.285714285714286f   // 1/0.07, also the fixed LSE max (|cos|<=1)

// ---------------------------------------------------------------------------
// Kernel 1: per-row inverse norms of q and k, plus diagonal logits.
// One block (256 threads) per row; each thread loads one float4 of q and k.
// ---------------------------------------------------------------------------
__global__ __launch_bounds__(256)
void norms_diag_kernel(const float* __restrict__ q, const float* __restrict__ k,
                       float* __restrict__ invq, float* __restrict__ invk,
                       float* __restrict__ diag) {
    const int row = blockIdx.x;
    const int tid = threadIdx.x;
    float4 a = *(const float4*)(q + (size_t)row * D + tid * 4);
    float4 b = *(const float4*)(k + (size_t)row * D + tid * 4);
    float sqq = a.x*a.x + a.y*a.y + a.z*a.z + a.w*a.w;
    float skk = b.x*b.x + b.y*b.y + b.z*b.z + b.w*b.w;
    float sqk = a.x*b.x + a.y*b.y + a.z*b.z + a.w*b.w;
    #pragma unroll
    for (int m = 1; m < 64; m <<= 1) {
        sqq += __shfl_xor(sqq, m, 64);
        skk += __shfl_xor(skk, m, 64);
        sqk += __shfl_xor(sqk, m, 64);
    }
    __shared__ float red[3][4];
    const int wid = tid >> 6, lane = tid & 63;
    if (lane == 0) { red[0][wid] = sqq; red[1][wid] = skk; red[2][wid] = sqk; }
    __syncthreads();
    if (tid == 0) {
        float s0 = red[0][0] + red[0][1] + red[0][2] + red[0][3];
        float s1 = red[1][0] + red[1][1] + red[1][2] + red[1][3];
        float s2 = red[2][0] + red[2][1] + red[2][2] + red[2][3];
        float iq = 1.0f / fmaxf(sqrtf(s0), 1e-12f);
        float ik = 1.0f / fmaxf(sqrtf(s1), 1e-12f);
        invq[row] = iq;
        invk[row] = ik;
        diag[row] = s2 * iq * ik * INV_T;
    }
}

// ---------------------------------------------------------------------------
// Kernel 2: tiled fp32 GEMM (q . k^T), fused scale + exp(logit - M) + row/col
// partial sums. 128x128 tile per block, 256 threads, 8x8 micro-tile/thread.
// LDS layout transposed [KB][132] so compute reads are float4 (ds_read_b128).
// ---------------------------------------------------------------------------
#define BT 128
#define KB 16
#define LDT 132   // pad: bank = (4*kc + row) % 32 -> 2-way on stores (free)

__global__ __launch_bounds__(256)
void gemm_lse_kernel(const float* __restrict__ q, const float* __restrict__ k,
                     const float* __restrict__ invq, const float* __restrict__ invk,
                     float* __restrict__ rowsum, float* __restrict__ colsum) {
    __shared__ float As[KB * LDT];
    __shared__ float Bs[KB * LDT];

    const int tid = threadIdx.x;
    const int tx = tid & 15;       // col group
    const int ty = tid >> 4;       // row group
    const int bi = blockIdx.y;     // row tile
    const int bj = blockIdx.x;     // col tile

    const float* qb = q + (size_t)(bi * BT) * D;
    const float* kb = k + (size_t)(bj * BT) * D;

    float acc[8][8] = {};

    for (int k0 = 0; k0 < D; k0 += KB) {
        // --- stage 128x16 of each matrix into transposed LDS ---
        #pragma unroll
        for (int i = 0; i < 2; ++i) {
            int idx  = tid + i * 256;       // 0..511
            int row  = idx >> 2;            // 0..127
            int kc4  = idx & 3;             // float4 index within the 16-wide K slab
            float4 av = *(const float4*)(qb + (size_t)row * D + k0 + kc4 * 4);
            float4 bv = *(const float4*)(kb + (size_t)row * D + k0 + kc4 * 4);
            int base = (kc4 * 4) * LDT + row;
            As[base          ] = av.x;  As[base +     LDT] = av.y;
            As[base + 2 * LDT] = av.z;  As[base + 3 * LDT] = av.w;
            Bs[base          ] = bv.x;  Bs[base +     LDT] = bv.y;
            Bs[base + 2 * LDT] = bv.z;  Bs[base + 3 * LDT] = bv.w;
        }
        __syncthreads();

        #pragma unroll
        for (int kk = 0; kk < KB; ++kk) {
            const float* ap = &As[kk * LDT + ty * 8];
            const float* bp = &Bs[kk * LDT + tx * 8];
            float4 a0 = *(const float4*)(ap);
            float4 a1 = *(const float4*)(ap + 4);
            float4 b0 = *(const float4*)(bp);
            float4 b1 = *(const float4*)(bp + 4);
            float ar[8] = {a0.x, a0.y, a0.z, a0.w, a1.x, a1.y, a1.z, a1.w};
            float br[8] = {b0.x, b0.y, b0.z, b0.w, b1.x, b1.y, b1.z, b1.w};
            #pragma unroll
            for (int r = 0; r < 8; ++r)
                #pragma unroll
                for (int c = 0; c < 8; ++c)
                    acc[r][c] += ar[r] * br[c];
        }
        __syncthreads();
    }

    // --- epilogue: scale, exp with fixed max, row/col partial sums ---
    float iqr[8], ikc[8];
    #pragma unroll
    for (int r = 0; r < 8; ++r) iqr[r] = invq[bi * BT + ty * 8 + r] * INV_T;
    #pragma unroll
    for (int c = 0; c < 8; ++c) ikc[c] = invk[bj * BT + tx * 8 + c];

    float rowpart[8] = {};
    float colpart[8] = {};
    #pragma unroll
    for (int r = 0; r < 8; ++r) {
        #pragma unroll
        for (int c = 0; c < 8; ++c) {
            float e = __expf(acc[r][c] * iqr[r] * ikc[c] - INV_T);
            rowpart[r] += e;
            colpart[c] += e;
        }
    }

    // rows: reduce across the 16 tx lanes (same wave), then one atomic per row
    #pragma unroll
    for (int r = 0; r < 8; ++r) {
        float v = rowpart[r];
        v += __shfl_xor(v, 1, 64);
        v += __shfl_xor(v, 2, 64);
        v += __shfl_xor(v, 4, 64);
        v += __shfl_xor(v, 8, 64);
        if (tx == 0) atomicAdd(&rowsum[bi * BT + ty * 8 + r], v);
    }

    // cols: reduce across ty (spans waves) via LDS, then one atomic per col
    __syncthreads();                 // done with As/Bs
    float* colbuf = As;              // 16*128 floats <= KB*LDT
    #pragma unroll
    for (int c = 0; c < 8; ++c) colbuf[ty * 128 + tx * 8 + c] = colpart[c];
    __syncthreads();
    if (tid < 128) {
        float s = 0.f;
        #pragma unroll
        for (int t2 = 0; t2 < 16; ++t2) s += colbuf[t2 * 128 + tid];
        atomicAdd(&colsum[bj * BT + tid], s);
    }
}

// ---------------------------------------------------------------------------
// Kernel 3: loss = M + ( 0.5*sum(log rs + log cs) - sum(diag) ) / N
// ---------------------------------------------------------------------------
__global__ __launch_bounds__(1024)
void final_kernel(const float* __restrict__ rowsum, const float* __restrict__ colsum,
                  const float* __restrict__ diag, float* __restrict__ out) {
    const int tid = threadIdx.x;
    float p = 0.f;
    for (int i = tid; i < N; i += 1024)
        p += 0.5f * (logf(rowsum[i]) + logf(colsum[i])) - diag[i];
    #pragma unroll
    for (int m = 1; m < 64; m <<= 1) p += __shfl_xor(p, m, 64);
    __shared__ float red[16];
    const int wid = tid >> 6, lane = tid & 63;
    if (lane == 0) red[wid] = p;
    __syncthreads();
    if (tid == 0) {
        float t = 0.f;
        #pragma unroll
        for (int w = 0; w < 16; ++w) t += red[w];
        out[0] = INV_T + t / (float)N;
    }
}

// ---------------------------------------------------------------------------
extern "C" void kernel_launch(void* const* d_in, const int* in_sizes, int n_in,
                              void* d_out, int out_size, void* d_ws, size_t ws_size,
                              hipStream_t stream) {
    const float* q = (const float*)d_in[0];
    const float* k = (const float*)d_in[1];
    float* ws     = (float*)d_ws;

    float* invq   = ws;             // [N]
    float* invk   = ws + N;         // [N]
    float* rowsum = ws + 2 * N;     // [N]
    float* colsum = ws + 3 * N;     // [N]
    float* diag   = ws + 4 * N;     // [N]

    // ws is re-poisoned to 0xAA before every timed launch — zero the accumulators.
    hipMemsetAsync(rowsum, 0, 2 * N * sizeof(float), stream);

    norms_diag_kernel<<<N, 256, 0, stream>>>(q, k, invq, invk, diag);
    gemm_lse_kernel<<<dim3(N / BT, N / BT), 256, 0, stream>>>(q, k, invq, invk,
                                                              rowsum, colsum);
    final_kernel<<<1, 1024, 0, stream>>>(rowsum, colsum, diag, (float*)d_out);
}

// Round 3
// 551.589 us; speedup vs baseline: 2.8080x; 2.8080x over previous
//
#include <hip/hip_runtime.h>
#include <math.h>

#define N 8192
#define D 1024
#define INV_T 14.285714285714286f   // 1/0.07; also the fixed LSE max (|cos|<=1)

typedef unsigned short ushortT;
typedef unsigned int uintT;
typedef __bf16 bf16x8 __attribute__((ext_vector_type(8)));
typedef float f32x4 __attribute__((ext_vector_type(4)));

#define AS1 __attribute__((address_space(1)))
#define AS3 __attribute__((address_space(3)))

__device__ __forceinline__ ushortT f2bf(float x) {
    uintT u = __float_as_uint(x);
    return (ushortT)((u + 0x7fffu + ((u >> 16) & 1u)) >> 16);   // RNE
}
__device__ __forceinline__ float bf2f(ushortT h) {
    return __uint_as_float(((uintT)h) << 16);
}

// ===========================================================================
// FAST PATH (needs ~64.1 MB of ws)
// ===========================================================================

// ---------------------------------------------------------------------------
// Kernel 1: per-row L2-normalize q,k; write bf16 hi/lo splits; diag logits.
// One block per row, 256 threads, each owns one float4.
// ---------------------------------------------------------------------------
__global__ __launch_bounds__(256)
void normalize_split_kernel(const float* __restrict__ q, const float* __restrict__ k,
                            ushortT* __restrict__ qs, ushortT* __restrict__ ks,
                            float* __restrict__ diag) {
    const int row = blockIdx.x;
    const int tid = threadIdx.x;
    const float4 a = *(const float4*)(q + (size_t)row * D + tid * 4);
    const float4 b = *(const float4*)(k + (size_t)row * D + tid * 4);
    float sqq = a.x*a.x + a.y*a.y + a.z*a.z + a.w*a.w;
    float skk = b.x*b.x + b.y*b.y + b.z*b.z + b.w*b.w;
    float sqk = a.x*b.x + a.y*b.y + a.z*b.z + a.w*b.w;
    #pragma unroll
    for (int m = 1; m < 64; m <<= 1) {
        sqq += __shfl_xor(sqq, m, 64);
        skk += __shfl_xor(skk, m, 64);
        sqk += __shfl_xor(sqk, m, 64);
    }
    __shared__ float red[3][4];
    __shared__ float s_iq, s_ik;
    const int wid = tid >> 6, lane = tid & 63;
    if (lane == 0) { red[0][wid] = sqq; red[1][wid] = skk; red[2][wid] = sqk; }
    __syncthreads();
    if (tid == 0) {
        float s0 = red[0][0] + red[0][1] + red[0][2] + red[0][3];
        float s1 = red[1][0] + red[1][1] + red[1][2] + red[1][3];
        float s2 = red[2][0] + red[2][1] + red[2][2] + red[2][3];
        float iq = 1.0f / fmaxf(sqrtf(s0), 1e-12f);
        float ik = 1.0f / fmaxf(sqrtf(s1), 1e-12f);
        s_iq = iq; s_ik = ik;
        diag[row] = s2 * iq * ik * INV_T;
    }
    __syncthreads();
    const float iq = s_iq, ik = s_ik;

    const size_t base = (size_t)row * D + tid * 4;
    const size_t LO = (size_t)N * D;
    float av[4] = {a.x * iq, a.y * iq, a.z * iq, a.w * iq};
    float bv[4] = {b.x * ik, b.y * ik, b.z * ik, b.w * ik};
    ushort4 qh, ql, kh, kl;
    ushortT* qhp = (ushortT*)&qh; ushortT* qlp = (ushortT*)&ql;
    ushortT* khp = (ushortT*)&kh; ushortT* klp = (ushortT*)&kl;
    #pragma unroll
    for (int j = 0; j < 4; ++j) {
        ushortT h = f2bf(av[j]); qhp[j] = h; qlp[j] = f2bf(av[j] - bf2f(h));
        ushortT g = f2bf(bv[j]); khp[j] = g; klp[j] = f2bf(bv[j] - bf2f(g));
    }
    *(ushort4*)(qs + base)      = qh;
    *(ushort4*)(qs + LO + base) = ql;
    *(ushort4*)(ks + base)      = kh;
    *(ushort4*)(ks + LO + base) = kl;
}

// ---------------------------------------------------------------------------
// Kernel 2: MFMA split-bf16 GEMM (qn . kn^T) with fused exp + row/col sums.
// 128x128 tile, 4 waves (2x2), BK=32. LDS rows are 128B = [hi(64B)|lo(64B)],
// XOR-swizzled (slot ^= row&7) via pre-swizzled global_load_lds source addrs.
// 3 MFMA passes per fragment: hi*hi + hi*lo + lo*hi.
// ---------------------------------------------------------------------------
#define BT 128
#define BK 32

__global__ __launch_bounds__(256)
void mfma_lse_kernel(const ushortT* __restrict__ qs, const ushortT* __restrict__ ks,
                     float* __restrict__ rowsum, float* __restrict__ colsum) {
    __shared__ __align__(16) char smemA[BT * 128];   // 16 KB
    __shared__ __align__(16) char smemB[BT * 128];   // 16 KB

    // XCD-chunked swizzle: 4096 wgs, 8 XCDs, 512 per XCD
    const int wg  = blockIdx.x;
    const int swz = (wg & 7) * 512 + (wg >> 3);
    const int bi  = swz >> 6;
    const int bj  = swz & 63;

    const int tid  = threadIdx.x;
    const int w    = tid >> 6;
    const int lane = tid & 63;
    const int wr   = w >> 1, wc = w & 1;
    const int la   = lane & 15, lq = lane >> 4;

    // --- staging: pre-swizzled global element offsets (16B granules) ---
    const size_t LO = (size_t)N * D;
    size_t aoff[4], boff[4];
    #pragma unroll
    for (int i = 0; i < 4; ++i) {
        int lin = i * 256 + tid;        // linear 16B-granule index, 0..1023
        int r   = lin >> 3;             // LDS row 0..127 (128B rows)
        int s   = lin & 7;              // physical slot
        int sp  = s ^ (r & 7);          // logical slot (involution)
        size_t hl = (sp >> 2) ? LO : 0; // slots 0-3 = hi, 4-7 = lo
        int kq  = (sp & 3) * 8;         // k element offset within tile
        aoff[i] = hl + (size_t)(bi * BT + r) * D + kq;
        boff[i] = hl + (size_t)(bj * BT + r) * D + kq;
    }

    // --- fragment LDS byte offsets (K-independent) ---
    int byteAh[4], byteAl[4], byteBh[4], byteBl[4];
    #pragma unroll
    for (int f = 0; f < 4; ++f) {
        int ra = wr * 64 + f * 16 + la;
        byteAh[f] = ra * 128 + ((lq       ^ (ra & 7)) * 16);
        byteAl[f] = ra * 128 + (((lq + 4) ^ (ra & 7)) * 16);
        int rb = wc * 64 + f * 16 + la;
        byteBh[f] = rb * 128 + ((lq       ^ (rb & 7)) * 16);
        byteBl[f] = rb * 128 + (((lq + 4) ^ (rb & 7)) * 16);
    }

    f32x4 acc[4][4] = {};

    for (int k0 = 0; k0 < D; k0 += BK) {
        #pragma unroll
        for (int i = 0; i < 4; ++i) {
            __builtin_amdgcn_global_load_lds(
                (const AS1 void*)(qs + aoff[i] + k0),
                (AS3 void*)(smemA + (i * 256 + w * 64) * 16), 16, 0, 0);
            __builtin_amdgcn_global_load_lds(
                (const AS1 void*)(ks + boff[i] + k0),
                (AS3 void*)(smemB + (i * 256 + w * 64) * 16), 16, 0, 0);
        }
        __syncthreads();

        bf16x8 ah[4], al[4], bh[4], bl[4];
        #pragma unroll
        for (int f = 0; f < 4; ++f) {
            ah[f] = *(const bf16x8*)(smemA + byteAh[f]);
            al[f] = *(const bf16x8*)(smemA + byteAl[f]);
            bh[f] = *(const bf16x8*)(smemB + byteBh[f]);
            bl[f] = *(const bf16x8*)(smemB + byteBl[f]);
        }
        #pragma unroll
        for (int m = 0; m < 4; ++m)
            #pragma unroll
            for (int n = 0; n < 4; ++n) {
                acc[m][n] = __builtin_amdgcn_mfma_f32_16x16x32_bf16(ah[m], bh[n], acc[m][n], 0, 0, 0);
                acc[m][n] = __builtin_amdgcn_mfma_f32_16x16x32_bf16(ah[m], bl[n], acc[m][n], 0, 0, 0);
                acc[m][n] = __builtin_amdgcn_mfma_f32_16x16x32_bf16(al[m], bh[n], acc[m][n], 0, 0, 0);
            }
        __syncthreads();
    }

    // --- epilogue: e = exp((cos-1)/T); row/col partial sums; atomics ---
    #pragma unroll
    for (int m = 0; m < 4; ++m)
        #pragma unroll
        for (int n = 0; n < 4; ++n)
            #pragma unroll
            for (int r = 0; r < 4; ++r)
                acc[m][n][r] = __expf((acc[m][n][r] - 1.0f) * INV_T);

    // rows: D-row = (lane>>4)*4 + reg; cols spread over la. Reduce over la.
    #pragma unroll
    for (int m = 0; m < 4; ++m)
        #pragma unroll
        for (int r = 0; r < 4; ++r) {
            float v = acc[m][0][r] + acc[m][1][r] + acc[m][2][r] + acc[m][3][r];
            v += __shfl_xor(v, 1, 64);
            v += __shfl_xor(v, 2, 64);
            v += __shfl_xor(v, 4, 64);
            v += __shfl_xor(v, 8, 64);
            if (la == 0)
                atomicAdd(&rowsum[bi * BT + wr * 64 + m * 16 + lq * 4 + r], v);
        }

    // cols: D-col = la; rows spread over lq. Reduce over lq.
    #pragma unroll
    for (int n = 0; n < 4; ++n) {
        float v = 0.f;
        #pragma unroll
        for (int m = 0; m < 4; ++m)
            #pragma unroll
            for (int r = 0; r < 4; ++r)
                v += acc[m][n][r];
        v += __shfl_xor(v, 16, 64);
        v += __shfl_xor(v, 32, 64);
        if (lq == 0)
            atomicAdd(&colsum[bj * BT + wc * 64 + n * 16 + la], v);
    }
}

// ---------------------------------------------------------------------------
// Kernel 3: loss = M + ( 0.5*sum(log rs + log cs) - sum(diag) ) / N
// ---------------------------------------------------------------------------
__global__ __launch_bounds__(1024)
void final_kernel(const float* __restrict__ rowsum, const float* __restrict__ colsum,
                  const float* __restrict__ diag, float* __restrict__ out) {
    const int tid = threadIdx.x;
    float p = 0.f;
    for (int i = tid; i < N; i += 1024)
        p += 0.5f * (logf(rowsum[i]) + logf(colsum[i])) - diag[i];
    #pragma unroll
    for (int m = 1; m < 64; m <<= 1) p += __shfl_xor(p, m, 64);
    __shared__ float red[16];
    const int wid = tid >> 6, lane = tid & 63;
    if (lane == 0) red[wid] = p;
    __syncthreads();
    if (tid == 0) {
        float t = 0.f;
        #pragma unroll
        for (int w = 0; w < 16; ++w) t += red[w];
        out[0] = INV_T + t / (float)N;
    }
}

// ===========================================================================
// FALLBACK PATH (fp32 VALU GEMM, needs only 5*N floats of ws) — round-1 code
// ===========================================================================
__global__ __launch_bounds__(256)
void norms_diag_kernel(const float* __restrict__ q, const float* __restrict__ k,
                       float* __restrict__ invq, float* __restrict__ invk,
                       float* __restrict__ diag) {
    const int row = blockIdx.x;
    const int tid = threadIdx.x;
    float4 a = *(const float4*)(q + (size_t)row * D + tid * 4);
    float4 b = *(const float4*)(k + (size_t)row * D + tid * 4);
    float sqq = a.x*a.x + a.y*a.y + a.z*a.z + a.w*a.w;
    float skk = b.x*b.x + b.y*b.y + b.z*b.z + b.w*b.w;
    float sqk = a.x*b.x + a.y*b.y + a.z*b.z + a.w*b.w;
    #pragma unroll
    for (int m = 1; m < 64; m <<= 1) {
        sqq += __shfl_xor(sqq, m, 64);
        skk += __shfl_xor(skk, m, 64);
        sqk += __shfl_xor(sqk, m, 64);
    }
    __shared__ float red[3][4];
    const int wid = tid >> 6, lane = tid & 63;
    if (lane == 0) { red[0][wid] = sqq; red[1][wid] = skk; red[2][wid] = sqk; }
    __syncthreads();
    if (tid == 0) {
        float s0 = red[0][0] + red[0][1] + red[0][2] + red[0][3];
        float s1 = red[1][0] + red[1][1] + red[1][2] + red[1][3];
        float s2 = red[2][0] + red[2][1] + red[2][2] + red[2][3];
        float iq = 1.0f / fmaxf(sqrtf(s0), 1e-12f);
        float ik = 1.0f / fmaxf(sqrtf(s1), 1e-12f);
        invq[row] = iq; invk[row] = ik;
        diag[row] = s2 * iq * ik * INV_T;
    }
}

#define KBF 16
#define LDTF 132
__global__ __launch_bounds__(256)
void gemm_lse_kernel(const float* __restrict__ q, const float* __restrict__ k,
                     const float* __restrict__ invq, const float* __restrict__ invk,
                     float* __restrict__ rowsum, float* __restrict__ colsum) {
    __shared__ float As[KBF * LDTF];
    __shared__ float Bs[KBF * LDTF];
    const int tid = threadIdx.x;
    const int tx = tid & 15;
    const int ty = tid >> 4;
    const int bi = blockIdx.y;
    const int bj = blockIdx.x;
    const float* qb = q + (size_t)(bi * BT) * D;
    const float* kb = k + (size_t)(bj * BT) * D;
    float acc[8][8] = {};
    for (int k0 = 0; k0 < D; k0 += KBF) {
        #pragma unroll
        for (int i = 0; i < 2; ++i) {
            int idx  = tid + i * 256;
            int row  = idx >> 2;
            int kc4  = idx & 3;
            float4 av = *(const float4*)(qb + (size_t)row * D + k0 + kc4 * 4);
            float4 bv = *(const float4*)(kb + (size_t)row * D + k0 + kc4 * 4);
            int base = (kc4 * 4) * LDTF + row;
            As[base] = av.x; As[base + LDTF] = av.y; As[base + 2*LDTF] = av.z; As[base + 3*LDTF] = av.w;
            Bs[base] = bv.x; Bs[base + LDTF] = bv.y; Bs[base + 2*LDTF] = bv.z; Bs[base + 3*LDTF] = bv.w;
        }
        __syncthreads();
        #pragma unroll
        for (int kk = 0; kk < KBF; ++kk) {
            const float* ap = &As[kk * LDTF + ty * 8];
            const float* bp = &Bs[kk * LDTF + tx * 8];
            float4 a0 = *(const float4*)(ap);
            float4 a1 = *(const float4*)(ap + 4);
            float4 b0 = *(const float4*)(bp);
            float4 b1 = *(const float4*)(bp + 4);
            float ar[8] = {a0.x, a0.y, a0.z, a0.w, a1.x, a1.y, a1.z, a1.w};
            float br[8] = {b0.x, b0.y, b0.z, b0.w, b1.x, b1.y, b1.z, b1.w};
            #pragma unroll
            for (int r = 0; r < 8; ++r)
                #pragma unroll
                for (int c = 0; c < 8; ++c)
                    acc[r][c] += ar[r] * br[c];
        }
        __syncthreads();
    }
    float iqr[8], ikc[8];
    #pragma unroll
    for (int r = 0; r < 8; ++r) iqr[r] = invq[bi * BT + ty * 8 + r] * INV_T;
    #pragma unroll
    for (int c = 0; c < 8; ++c) ikc[c] = invk[bj * BT + tx * 8 + c];
    float rowpart[8] = {};
    float colpart[8] = {};
    #pragma unroll
    for (int r = 0; r < 8; ++r)
        #pragma unroll
        for (int c = 0; c < 8; ++c) {
            float e = __expf(acc[r][c] * iqr[r] * ikc[c] - INV_T);
            rowpart[r] += e; colpart[c] += e;
        }
    #pragma unroll
    for (int r = 0; r < 8; ++r) {
        float v = rowpart[r];
        v += __shfl_xor(v, 1, 64); v += __shfl_xor(v, 2, 64);
        v += __shfl_xor(v, 4, 64); v += __shfl_xor(v, 8, 64);
        if (tx == 0) atomicAdd(&rowsum[bi * BT + ty * 8 + r], v);
    }
    __syncthreads();
    float* colbuf = As;
    #pragma unroll
    for (int c = 0; c < 8; ++c) colbuf[ty * 128 + tx * 8 + c] = colpart[c];
    __syncthreads();
    if (tid < 128) {
        float s = 0.f;
        #pragma unroll
        for (int t2 = 0; t2 < 16; ++t2) s += colbuf[t2 * 128 + tid];
        atomicAdd(&colsum[bj * BT + tid], s);
    }
}

// ===========================================================================
extern "C" void kernel_launch(void* const* d_in, const int* in_sizes, int n_in,
                              void* d_out, int out_size, void* d_ws, size_t ws_size,
                              hipStream_t stream) {
    const float* q = (const float*)d_in[0];
    const float* k = (const float*)d_in[1];

    const size_t splitBytes = 4ull * N * D * sizeof(ushortT);   // 64 MB
    const size_t needFast   = splitBytes + 3ull * N * sizeof(float);

    if (ws_size >= needFast) {
        ushortT* qs = (ushortT*)d_ws;                       // qh | ql
        ushortT* ks = qs + 2ull * N * D;                    // kh | kl
        float* tail  = (float*)((char*)d_ws + splitBytes);
        float* rowsum = tail;
        float* colsum = tail + N;
        float* diag   = tail + 2 * N;

        hipMemsetAsync(rowsum, 0, 2ull * N * sizeof(float), stream);
        normalize_split_kernel<<<N, 256, 0, stream>>>(q, k, qs, ks, diag);
        mfma_lse_kernel<<<(N / BT) * (N / BT), 256, 0, stream>>>(qs, ks, rowsum, colsum);
        final_kernel<<<1, 1024, 0, stream>>>(rowsum, colsum, diag, (float*)d_out);
    } else {
        float* ws     = (float*)d_ws;
        float* invq   = ws;
        float* invk   = ws + N;
        float* rowsum = ws + 2 * N;
        float* colsum = ws + 3 * N;
        float* diag   = ws + 4 * N;
        hipMemsetAsync(rowsum, 0, 2ull * N * sizeof(float), stream);
        norms_diag_kernel<<<N, 256, 0, stream>>>(q, k, invq, invk, diag);
        gemm_lse_kernel<<<dim3(N / BT, N / BT), 256, 0, stream>>>(q, k, invq, invk, rowsum, colsum);
        final_kernel<<<1, 1024, 0, stream>>>(rowsum, colsum, diag, (float*)d_out);
    }
}